// Round 6
// baseline (917.140 us; speedup 1.0000x reference)
//
#include <hip/hip_runtime.h>
#include <hip/hip_fp16.h>
#include <hip/hip_cooperative_groups.h>

namespace cg = cooperative_groups;

constexpr int ES = 7;
constexpr int CH = 256;
constexpr int FH = 200;
constexpr int FW = 304;
constexpr int HW = FH * FW;             // 60800
constexpr int CELLS = ES * ES;          // 49
constexpr int BOX_OUT = CH * CELLS;     // 12544 floats
constexpr int QCH = 64;                 // channels per gather quarter
constexpr int HW_TILES = HW / 64;       // 950
constexpr int CT_TILES = CH / 64;       // 4
constexpr int TILES_PER_BATCH = HW_TILES * CT_TILES;   // 3800
constexpr int GRID_BLOCKS = 1536;       // 6 blocks/CU x 256 CU

struct TransSmem {
  float s_t[64][65];
};
struct GatherSmem {
  int   y0[ES]; int y1[ES]; int x0[ES];
  float fy[ES]; float fx[ES];
  alignas(16) float buf[QCH * CELLS];   // 12544 B
};
union ComboSmem {
  TransSmem t;
  GatherSmem g;
};

// ---------------------------------------------------------------------------
// Single cooperative pipeline kernel.
// P0: T(0) | P1: G(0)+T(1) | P2: G(1)+T(2) | P3: G(2)+T(3) | P4: G(3)
// T(b) writes fmt buffer (b&1); G(b) reads it next phase (L3-hot).
// Transpose tiles claimed via global atomic tickets (self-load-balancing
// against the data-dependent gather work). grid.sync() between phases.
// ---------------------------------------------------------------------------
__global__ __launch_bounds__(256, 6)
void roi_pipeline_kernel(const float* __restrict__ fm,
                         __half* __restrict__ fmtA,
                         __half* __restrict__ fmtB,
                         const float* __restrict__ boxes,
                         const int* __restrict__ assoc,
                         float* __restrict__ out,
                         unsigned int* __restrict__ tickets,
                         int n_boxes) {
  __shared__ ComboSmem smem;
  __shared__ int s_tile;
  cg::grid_group grid = cg::this_grid();
  const int t = threadIdx.x;

  for (int ph = 0; ph < 5; ++ph) {
    // ---------------- gather batch (ph-1) ----------------
    if (ph >= 1) {
      const int gb = ph - 1;
      const __half* fmtg = (gb & 1) ? fmtB : fmtA;
      const int n_items = n_boxes * 4;
      for (int item = blockIdx.x; item < n_items; item += GRID_BLOCKS) {
        const int n = item >> 2;
        if (assoc[n] != gb) continue;          // block-uniform skip
        const int q = item & 3;
        GatherSmem& g = smem.g;
        __syncthreads();                        // protect smem reuse
        if (t < 2 * ES) {
          const int axis = t / ES;   // 0 = y, 1 = x
          const int i = t % ES;
          const float start = boxes[n * 4 + axis];
          const float stop  = boxes[n * 4 + 2 + axis];
          const float step  = (stop - start) * (1.0f / (float)(ES - 1));
          const float cc = fminf((float)i * step + start, stop);
          const float fl = floorf(cc);
          if (axis == 0) {
            g.y0[i] = (int)fl;
            g.y1[i] = (int)ceilf(cc);
            g.fy[i] = cc - fl;
          } else {
            int x0 = (int)fl;
            float f = cc - fl;
            if (x0 >= FW - 1) { x0 = FW - 2; f = 1.0f; }
            g.x0[i] = x0;
            g.fx[i] = f;
          }
        }
        __syncthreads();

        const int cgi = t & 7;     // 8-channel group within the quarter
        const int sub = t >> 3;    // cell phase 0..31
        const __half* base = fmtg + q * QCH + cgi * 8;

        for (int cell = sub; cell < CELLS; cell += 32) {
          const int i = cell / ES;
          const int j = cell % ES;
          const int y0 = g.y0[i], y1 = g.y1[i], x0 = g.x0[j];
          const float fy = g.fy[i], fx = g.fx[j];
          const float w00 = (1.0f - fy) * (1.0f - fx);
          const float w01 = (1.0f - fy) * fx;
          const float w10 = fy * (1.0f - fx);
          const float w11 = fy * fx;

          const size_t o0 = (size_t)(y0 * FW + x0) * CH;
          const size_t o1 = (size_t)(y1 * FW + x0) * CH;
          const uint4 q00 = *(const uint4*)(base + o0);
          const uint4 q01 = *(const uint4*)(base + o0 + CH);
          const uint4 q10 = *(const uint4*)(base + o1);
          const uint4 q11 = *(const uint4*)(base + o1 + CH);

          const __half2* a00 = (const __half2*)&q00;
          const __half2* a01 = (const __half2*)&q01;
          const __half2* a10 = (const __half2*)&q10;
          const __half2* a11 = (const __half2*)&q11;

          const int lc = cgi * 8;
          #pragma unroll
          for (int p = 0; p < 4; ++p) {
            const float2 f00 = __half22float2(a00[p]);
            const float2 f01 = __half22float2(a01[p]);
            const float2 f10 = __half22float2(a10[p]);
            const float2 f11 = __half22float2(a11[p]);
            const float rx = w00 * f00.x + w01 * f01.x + w10 * f10.x + w11 * f11.x;
            const float ry = w00 * f00.y + w01 * f01.y + w10 * f10.y + w11 * f11.y;
            g.buf[(lc + 2 * p + 0) * CELLS + cell] = rx;
            g.buf[(lc + 2 * p + 1) * CELLS + cell] = ry;
          }
        }
        __syncthreads();

        float4* __restrict__ outv =
            (float4*)(out + (size_t)n * BOX_OUT + (size_t)q * QCH * CELLS);
        const float4* bufv = (const float4*)g.buf;
        for (int k = t; k < QCH * CELLS / 4; k += 256) {
          outv[k] = bufv[k];
        }
      }
    }

    // ---------------- transpose batch ph (ticketed) ----------------
    if (ph < 4) {
      __half* fmtw = (ph & 1) ? fmtB : fmtA;
      unsigned int* ticket = tickets + ph;
      while (true) {
        __syncthreads();                        // protect s_tile + smem reuse
        if (t == 0) s_tile = (int)atomicAdd(ticket, 1u);
        __syncthreads();
        const int tile = s_tile;
        if (tile >= TILES_PER_BATCH) break;
        const int hwt = (tile % HW_TILES) * 64;
        const int ct  = (tile / HW_TILES) * 64;
        TransSmem& ts = smem.t;
        {
          const int hw4  = t % 16;
          const int c_lo = t / 16;
          #pragma unroll
          for (int rr = 0; rr < 4; ++rr) {
            const int c = c_lo + rr * 16;
            const float4 v = *(const float4*)(fm + ((size_t)(ph * CH + ct + c)) * HW
                                                 + hwt + hw4 * 4);
            ts.s_t[c][hw4 * 4 + 0] = v.x;
            ts.s_t[c][hw4 * 4 + 1] = v.y;
            ts.s_t[c][hw4 * 4 + 2] = v.z;
            ts.s_t[c][hw4 * 4 + 3] = v.w;
          }
        }
        __syncthreads();
        {
          const int c8 = t % 8;
          const int hl = t / 8;
          #pragma unroll
          for (int rr = 0; rr < 2; ++rr) {
            const int h = hl + rr * 32;
            union { uint4 u; __half hh[8]; } o;
            #pragma unroll
            for (int e = 0; e < 8; ++e) {
              o.hh[e] = __float2half(ts.s_t[c8 * 8 + e][h]);
            }
            *(uint4*)(fmtw + ((size_t)(hwt + h)) * CH + ct + c8 * 8) = o.u;
          }
        }
      }
    }

    if (ph < 4) grid.sync();
  }
}

// ---------------------------------------------------------------------------
// Plain-launch fallback path (R3 structure): full 4-batch transpose + gather.
// ---------------------------------------------------------------------------
__global__ __launch_bounds__(256)
void nchw_to_nhwc_f16_kernel(const float* __restrict__ fm,
                             __half* __restrict__ fmt) {
  __shared__ float s_t[64][65];
  const int t   = threadIdx.x;
  const int hwt = blockIdx.x * 64;
  const int ct  = blockIdx.y * 64;
  const int b   = blockIdx.z;
  {
    const int hw4  = t % 16;
    const int c_lo = t / 16;
    #pragma unroll
    for (int r = 0; r < 4; ++r) {
      const int c = c_lo + r * 16;
      const float4 v = *(const float4*)(fm + ((size_t)(b * CH + ct + c)) * HW
                                           + hwt + hw4 * 4);
      s_t[c][hw4 * 4 + 0] = v.x;
      s_t[c][hw4 * 4 + 1] = v.y;
      s_t[c][hw4 * 4 + 2] = v.z;
      s_t[c][hw4 * 4 + 3] = v.w;
    }
  }
  __syncthreads();
  {
    const int c8 = t % 8;
    const int hl = t / 8;
    #pragma unroll
    for (int r = 0; r < 2; ++r) {
      const int h = hl + r * 32;
      union { uint4 u; __half hh[8]; } o;
      #pragma unroll
      for (int e = 0; e < 8; ++e) {
        o.hh[e] = __float2half(s_t[c8 * 8 + e][h]);
      }
      *(uint4*)(fmt + ((size_t)b * HW + hwt + h) * CH + ct + c8 * 8) = o.u;
    }
  }
}

__global__ __launch_bounds__(256)
void roi_gather_nhwc_f16_kernel(const __half* __restrict__ fmt,
                                const float* __restrict__ boxes,
                                const int* __restrict__ assoc,
                                float* __restrict__ out) {
  __shared__ int   s_y0[ES];
  __shared__ int   s_y1[ES];
  __shared__ int   s_x0[ES];
  __shared__ float s_fy[ES];
  __shared__ float s_fx[ES];
  __shared__ __align__(16) float s_buf[BOX_OUT];

  const int n = blockIdx.x;
  const int t = threadIdx.x;

  if (t < 2 * ES) {
    const int axis = t / ES;
    const int i = t % ES;
    const float start = boxes[n * 4 + axis];
    const float stop  = boxes[n * 4 + 2 + axis];
    const float step  = (stop - start) * (1.0f / (float)(ES - 1));
    const float cc = fminf((float)i * step + start, stop);
    const float fl = floorf(cc);
    if (axis == 0) {
      s_y0[i] = (int)fl;
      s_y1[i] = (int)ceilf(cc);
      s_fy[i] = cc - fl;
    } else {
      int x0 = (int)fl;
      float f = cc - fl;
      if (x0 >= FW - 1) { x0 = FW - 2; f = 1.0f; }
      s_x0[i] = x0;
      s_fx[i] = f;
    }
  }
  __syncthreads();

  const int cg  = t & 31;
  const int sub = t >> 5;
  const int b   = assoc[n];
  const __half* base = fmt + (size_t)b * HW * CH + cg * 8;

  for (int cell = sub; cell < CELLS; cell += 8) {
    const int i = cell / ES;
    const int j = cell % ES;
    const int y0 = s_y0[i], y1 = s_y1[i], x0 = s_x0[j];
    const float fy = s_fy[i], fx = s_fx[j];
    const float w00 = (1.0f - fy) * (1.0f - fx);
    const float w01 = (1.0f - fy) * fx;
    const float w10 = fy * (1.0f - fx);
    const float w11 = fy * fx;

    const uint4 q00 = *(const uint4*)(base + (size_t)(y0 * FW + x0) * CH);
    const uint4 q01 = *(const uint4*)(base + (size_t)(y0 * FW + x0 + 1) * CH);
    const uint4 q10 = *(const uint4*)(base + (size_t)(y1 * FW + x0) * CH);
    const uint4 q11 = *(const uint4*)(base + (size_t)(y1 * FW + x0 + 1) * CH);

    const __half2* a00 = (const __half2*)&q00;
    const __half2* a01 = (const __half2*)&q01;
    const __half2* a10 = (const __half2*)&q10;
    const __half2* a11 = (const __half2*)&q11;

    #pragma unroll
    for (int p = 0; p < 4; ++p) {
      const float2 f00 = __half22float2(a00[p]);
      const float2 f01 = __half22float2(a01[p]);
      const float2 f10 = __half22float2(a10[p]);
      const float2 f11 = __half22float2(a11[p]);
      const float rx = w00 * f00.x + w01 * f01.x + w10 * f10.x + w11 * f11.x;
      const float ry = w00 * f00.y + w01 * f01.y + w10 * f10.y + w11 * f11.y;
      s_buf[(cg * 8 + 2 * p + 0) * CELLS + cell] = rx;
      s_buf[(cg * 8 + 2 * p + 1) * CELLS + cell] = ry;
    }
  }
  __syncthreads();

  float4* __restrict__ outv = (float4*)(out + (size_t)n * BOX_OUT);
  const float4* bufv = (const float4*)s_buf;
  for (int k = t; k < BOX_OUT / 4; k += 256) {
    outv[k] = bufv[k];
  }
}

// Ultimate fallback: direct NCHW gather (ws too small).
__global__ __launch_bounds__(256)
void roi_align_fallback_kernel(const float* __restrict__ fm,
                               const float* __restrict__ boxes,
                               const int* __restrict__ assoc,
                               float* __restrict__ out) {
  __shared__ int   s_y0[ES];
  __shared__ int   s_y1[ES];
  __shared__ int   s_x0[ES];
  __shared__ float s_fy[ES];
  __shared__ float s_fx[ES];
  __shared__ __align__(16) float s_buf[BOX_OUT];

  const int n = blockIdx.x;
  const int t = threadIdx.x;

  if (t < 2 * ES) {
    const int axis = t / ES;
    const int i = t % ES;
    const float start = boxes[n * 4 + axis];
    const float stop  = boxes[n * 4 + 2 + axis];
    const float step  = (stop - start) * (1.0f / (float)(ES - 1));
    const float cc = fminf((float)i * step + start, stop);
    const float fl = floorf(cc);
    if (axis == 0) {
      s_y0[i] = (int)fl;
      s_y1[i] = (int)ceilf(cc);
      s_fy[i] = cc - fl;
    } else {
      int x0 = (int)fl;
      float f = cc - fl;
      if (x0 >= FW - 1) { x0 = FW - 2; f = 1.0f; }
      s_x0[i] = x0;
      s_fx[i] = f;
    }
  }
  __syncthreads();

  const int c = t;
  const int b = assoc[n];
  const float* plane = fm + ((size_t)b * CH + c) * (size_t)HW;

  #pragma unroll
  for (int i = 0; i < ES; ++i) {
    const float* r0 = plane + s_y0[i] * FW;
    const float* r1 = plane + s_y1[i] * FW;
    const float fy = s_fy[i];
    #pragma unroll
    for (int j = 0; j < ES; ++j) {
      const int   x0 = s_x0[j];
      const float fx = s_fx[j];
      const float v00 = r0[x0];
      const float v01 = r0[x0 + 1];
      const float v10 = r1[x0];
      const float v11 = r1[x0 + 1];
      const float top = v00 + fx * (v01 - v00);
      const float bot = v10 + fx * (v11 - v10);
      s_buf[c * CELLS + i * ES + j] = top + fy * (bot - top);
    }
  }
  __syncthreads();

  float4* __restrict__ outv = (float4*)(out + (size_t)n * BOX_OUT);
  const float4* bufv = (const float4*)s_buf;
  for (int k = t; k < BOX_OUT / 4; k += 256) {
    outv[k] = bufv[k];
  }
}

extern "C" void kernel_launch(void* const* d_in, const int* in_sizes, int n_in,
                              void* d_out, int out_size, void* d_ws, size_t ws_size,
                              hipStream_t stream) {
  const float* fm    = (const float*)d_in[0];
  const float* boxes = (const float*)d_in[1];
  const int*   assoc = (const int*)d_in[2];
  float* out = (float*)d_out;
  int n_boxes = in_sizes[2];                       // 1024
  const int nbatch  = in_sizes[0] / (CH * HW);     // 4

  // ws layout: [4 x CH x HW halfs  (coop uses first 2 slots as A/B;
  //             fallback uses all 4 as contiguous NHWC)] [4 ticket uints]
  const size_t fmt_elems = (size_t)4 * CH * HW;
  const size_t need = fmt_elems * sizeof(__half) + 4 * sizeof(unsigned int);

  if (nbatch == 4 && ws_size >= need) {
    __half* fmtA = (__half*)d_ws;
    __half* fmtB = fmtA + (size_t)CH * HW;
    unsigned int* tickets = (unsigned int*)((char*)d_ws + fmt_elems * sizeof(__half));

    hipMemsetAsync(tickets, 0, 4 * sizeof(unsigned int), stream);
    void* args[] = {(void*)&fm, (void*)&fmtA, (void*)&fmtB, (void*)&boxes,
                    (void*)&assoc, (void*)&out, (void*)&tickets, (void*)&n_boxes};
    hipError_t e = hipLaunchCooperativeKernel((const void*)roi_pipeline_kernel,
                                              dim3(GRID_BLOCKS), dim3(256),
                                              args, 0, stream);
    if (e == hipSuccess) return;
    (void)hipGetLastError();   // clear and take the plain path

    __half* fmt = (__half*)d_ws;
    dim3 tgrid(HW / 64, CH / 64, 4);
    nchw_to_nhwc_f16_kernel<<<tgrid, 256, 0, stream>>>(fm, fmt);
    roi_gather_nhwc_f16_kernel<<<n_boxes, 256, 0, stream>>>(fmt, boxes, assoc, out);
  } else {
    roi_align_fallback_kernel<<<n_boxes, 256, 0, stream>>>(fm, boxes, assoc, out);
  }
}

// Round 7
// 83.615 us; speedup vs baseline: 10.9686x; 10.9686x over previous
//
#include <hip/hip_runtime.h>
#include <hip/hip_fp16.h>

constexpr int ES = 7;
constexpr int CH = 256;
constexpr int FH = 200;
constexpr int FW = 304;
constexpr int HW = FH * FW;             // 60800
constexpr int CELLS = ES * ES;          // 49
constexpr int BOX_OUT = CH * CELLS;     // 12544 floats
constexpr int QCH = 64;                 // channels per gather quarter

typedef float f32x4 __attribute__((ext_vector_type(4)));

// ---------------------------------------------------------------------------
// Kernel 1: NCHW f32 -> NHWC f16 transpose (all 4 batches).
// fm reads are NONTEMPORAL (streamed, no reuse) so they don't evict the
// freshly written fmt from L3. fmt writes allocate normally (gather reuses).
// 64(ch) x 64(hw) tiles, LDS padded [64][65] (2-way max = free on CDNA4).
// ---------------------------------------------------------------------------
__global__ __launch_bounds__(256)
void nchw_to_nhwc_f16_kernel(const float* __restrict__ fm,
                             __half* __restrict__ fmt) {
  __shared__ float s_t[64][65];
  const int t   = threadIdx.x;
  const int hwt = blockIdx.x * 64;
  const int ct  = blockIdx.y * 64;
  const int b   = blockIdx.z;

  // Phase 1: coalesced float4 nontemporal reads along hw.
  {
    const int hw4  = t % 16;
    const int c_lo = t / 16;
    #pragma unroll
    for (int r = 0; r < 4; ++r) {
      const int c = c_lo + r * 16;
      const f32x4 v = __builtin_nontemporal_load(
          (const f32x4*)(fm + ((size_t)(b * CH + ct + c)) * HW + hwt + hw4 * 4));
      s_t[c][hw4 * 4 + 0] = v.x;
      s_t[c][hw4 * 4 + 1] = v.y;
      s_t[c][hw4 * 4 + 2] = v.z;
      s_t[c][hw4 * 4 + 3] = v.w;
    }
  }
  __syncthreads();

  // Phase 2: gather 8 channels at fixed hw, convert to f16, 16B store.
  {
    const int c8 = t % 8;
    const int hl = t / 8;
    #pragma unroll
    for (int r = 0; r < 2; ++r) {
      const int h = hl + r * 32;
      union { uint4 u; __half hh[8]; } o;
      #pragma unroll
      for (int e = 0; e < 8; ++e) {
        o.hh[e] = __float2half(s_t[c8 * 8 + e][h]);
      }
      *(uint4*)(fmt + ((size_t)b * HW + hwt + h) * CH + ct + c8 * 8) = o.u;
    }
  }
}

// ---------------------------------------------------------------------------
// Kernel 2: RoI-align gather on NHWC f16, box-QUARTER granularity.
// Block = (box, 64-channel quarter): 4096 blocks x 12.5 KB LDS -> ~6-8
// blocks/CU of memory-level parallelism. Tap reads hit L3 (fmt resident);
// output stores are nontemporal (never re-read, keep L3 for fmt).
// ---------------------------------------------------------------------------
__global__ __launch_bounds__(256)
void roi_gather_q_kernel(const __half* __restrict__ fmt,
                         const float* __restrict__ boxes,
                         const int* __restrict__ assoc,
                         float* __restrict__ out) {
  __shared__ int   s_y0[ES];
  __shared__ int   s_y1[ES];
  __shared__ int   s_x0[ES];
  __shared__ float s_fy[ES];
  __shared__ float s_fx[ES];
  __shared__ __align__(16) float s_buf[QCH * CELLS];

  const int n = blockIdx.x;
  const int q = blockIdx.y;
  const int t = threadIdx.x;

  if (t < 2 * ES) {
    const int axis = t / ES;   // 0 = y, 1 = x
    const int i = t % ES;
    const float start = boxes[n * 4 + axis];
    const float stop  = boxes[n * 4 + 2 + axis];
    const float step  = (stop - start) * (1.0f / (float)(ES - 1));
    const float cc = fminf((float)i * step + start, stop);
    const float fl = floorf(cc);
    if (axis == 0) {
      s_y0[i] = (int)fl;
      s_y1[i] = (int)ceilf(cc);
      s_fy[i] = cc - fl;
    } else {
      int x0 = (int)fl;
      float f = cc - fl;
      if (x0 >= FW - 1) { x0 = FW - 2; f = 1.0f; }
      s_x0[i] = x0;
      s_fx[i] = f;
    }
  }
  __syncthreads();

  const int cgi = t & 7;     // 8-channel group within the quarter
  const int sub = t >> 3;    // cell phase 0..31
  const __half* base = fmt + (size_t)assoc[n] * HW * CH + q * QCH + cgi * 8;

  for (int cell = sub; cell < CELLS; cell += 32) {
    const int i = cell / ES;
    const int j = cell % ES;
    const int y0 = s_y0[i], y1 = s_y1[i], x0 = s_x0[j];
    const float fy = s_fy[i], fx = s_fx[j];
    const float w00 = (1.0f - fy) * (1.0f - fx);
    const float w01 = (1.0f - fy) * fx;
    const float w10 = fy * (1.0f - fx);
    const float w11 = fy * fx;

    const size_t o0 = (size_t)(y0 * FW + x0) * CH;
    const size_t o1 = (size_t)(y1 * FW + x0) * CH;
    const uint4 q00 = *(const uint4*)(base + o0);
    const uint4 q01 = *(const uint4*)(base + o0 + CH);
    const uint4 q10 = *(const uint4*)(base + o1);
    const uint4 q11 = *(const uint4*)(base + o1 + CH);

    const __half2* a00 = (const __half2*)&q00;
    const __half2* a01 = (const __half2*)&q01;
    const __half2* a10 = (const __half2*)&q10;
    const __half2* a11 = (const __half2*)&q11;

    const int lc = cgi * 8;
    #pragma unroll
    for (int p = 0; p < 4; ++p) {
      const float2 f00 = __half22float2(a00[p]);
      const float2 f01 = __half22float2(a01[p]);
      const float2 f10 = __half22float2(a10[p]);
      const float2 f11 = __half22float2(a11[p]);
      const float rx = w00 * f00.x + w01 * f01.x + w10 * f10.x + w11 * f11.x;
      const float ry = w00 * f00.y + w01 * f01.y + w10 * f10.y + w11 * f11.y;
      s_buf[(lc + 2 * p + 0) * CELLS + cell] = rx;
      s_buf[(lc + 2 * p + 1) * CELLS + cell] = ry;
    }
  }
  __syncthreads();

  // Coalesced nontemporal float4 stores of this quarter's (64,7,7) block.
  f32x4* __restrict__ outv =
      (f32x4*)(out + (size_t)n * BOX_OUT + (size_t)q * QCH * CELLS);
  const f32x4* bufv = (const f32x4*)s_buf;
  for (int k = t; k < QCH * CELLS / 4; k += 256) {
    __builtin_nontemporal_store(bufv[k], outv + k);
  }
}

// ---------------------------------------------------------------------------
// Fallback: direct NCHW gather (correct, slower) if ws too small.
// ---------------------------------------------------------------------------
__global__ __launch_bounds__(256)
void roi_align_fallback_kernel(const float* __restrict__ fm,
                               const float* __restrict__ boxes,
                               const int* __restrict__ assoc,
                               float* __restrict__ out) {
  __shared__ int   s_y0[ES];
  __shared__ int   s_y1[ES];
  __shared__ int   s_x0[ES];
  __shared__ float s_fy[ES];
  __shared__ float s_fx[ES];
  __shared__ __align__(16) float s_buf[BOX_OUT];

  const int n = blockIdx.x;
  const int t = threadIdx.x;

  if (t < 2 * ES) {
    const int axis = t / ES;
    const int i = t % ES;
    const float start = boxes[n * 4 + axis];
    const float stop  = boxes[n * 4 + 2 + axis];
    const float step  = (stop - start) * (1.0f / (float)(ES - 1));
    const float cc = fminf((float)i * step + start, stop);
    const float fl = floorf(cc);
    if (axis == 0) {
      s_y0[i] = (int)fl;
      s_y1[i] = (int)ceilf(cc);
      s_fy[i] = cc - fl;
    } else {
      int x0 = (int)fl;
      float f = cc - fl;
      if (x0 >= FW - 1) { x0 = FW - 2; f = 1.0f; }
      s_x0[i] = x0;
      s_fx[i] = f;
    }
  }
  __syncthreads();

  const int c = t;
  const int b = assoc[n];
  const float* plane = fm + ((size_t)b * CH + c) * (size_t)HW;

  #pragma unroll
  for (int i = 0; i < ES; ++i) {
    const float* r0 = plane + s_y0[i] * FW;
    const float* r1 = plane + s_y1[i] * FW;
    const float fy = s_fy[i];
    #pragma unroll
    for (int j = 0; j < ES; ++j) {
      const int   x0 = s_x0[j];
      const float fx = s_fx[j];
      const float v00 = r0[x0];
      const float v01 = r0[x0 + 1];
      const float v10 = r1[x0];
      const float v11 = r1[x0 + 1];
      const float top = v00 + fx * (v01 - v00);
      const float bot = v10 + fx * (v11 - v10);
      s_buf[c * CELLS + i * ES + j] = top + fy * (bot - top);
    }
  }
  __syncthreads();

  float4* __restrict__ outv = (float4*)(out + (size_t)n * BOX_OUT);
  const float4* bufv = (const float4*)s_buf;
  for (int k = t; k < BOX_OUT / 4; k += 256) {
    outv[k] = bufv[k];
  }
}

extern "C" void kernel_launch(void* const* d_in, const int* in_sizes, int n_in,
                              void* d_out, int out_size, void* d_ws, size_t ws_size,
                              hipStream_t stream) {
  const float* fm    = (const float*)d_in[0];
  const float* boxes = (const float*)d_in[1];
  const int*   assoc = (const int*)d_in[2];
  float* out = (float*)d_out;
  const int n_boxes = in_sizes[2];                 // 1024
  const int nbatch  = in_sizes[0] / (CH * HW);     // 4

  const size_t need = (size_t)nbatch * CH * HW * sizeof(__half);   // 124.5 MB
  if (ws_size >= need) {
    __half* fmt = (__half*)d_ws;
    dim3 tgrid(HW / 64, CH / 64, nbatch);
    nchw_to_nhwc_f16_kernel<<<tgrid, 256, 0, stream>>>(fm, fmt);
    dim3 ggrid(n_boxes, CH / QCH);
    roi_gather_q_kernel<<<ggrid, 256, 0, stream>>>(fmt, boxes, assoc, out);
  } else {
    roi_align_fallback_kernel<<<n_boxes, 256, 0, stream>>>(fm, boxes, assoc, out);
  }
}